// Round 13
// baseline (118.412 us; speedup 1.0000x reference)
//
#include <hip/hip_runtime.h>
#include <hip/hip_bf16.h>

// ---------------------------------------------------------------------------
// GCN 2-layer + BN + tanh. All dense streams bf16 (f32 accum).
//   init_k:    W -> bf16 transposed; zero-inits counters. (tiny)
//   partx_k:   [blocks 0..xcB)   x -> bf16 (BW-bound)
//              [blocks xcB..end) partition E edges into NB=256 dst-buckets
//              (CHUNK=1024, 4 edges/thread; coalesced 8B recs; staging spills
//              -> direct bucket slot).
//   binscat_k: per-bucket LDS scatter (512 thr) -> 4B bins (src:u16|w:bf16)+cnt.
//   spmm1_k:   one wave/row, half-wave per edge (ushort2 gathers), 1024-thr
//              blocks: agg_bf = bf16(sum w*x_bf[src]); ovf scan inline.
//   gemm1_k:   h_bf = bf16([agg|x] @ [W1rel;W1root] + b1) (MFMA, W in LDS
//              swizzled, 2 row-tiles/wave); BN partials -> f32 atomics.
//   gemm2_k:   per-block BN finalize; act=tanh fused; y2_bf=act@W2rel,
//              out=act@W2root+b2 (f32).
//   spmm2_k:   one wave/row, quarter-wave per edge, 1024-thr blocks.
// MFMA 16x16x32 bf16 lane maps (m89-verified D):
//   A: row=lane&15, k=8*(lane>>4)+i ; B: col=lane&15 (Wt[n][k]) ;
//   D: col=lane&15, row=4*(lane>>4)+reg
// LDS W swizzle: byte ^= (row&7)<<4  (256B per k-row)
// NOTE: 4B bin records assume N <= 65536 (harness N=50000).
// ---------------------------------------------------------------------------

#define NB 256
#define CAPB 4096
#define LCAP 16
#define CHUNK 1024
#define CAP 32
#define MAXROWS 196
#define OVF_CAP 131072

typedef __bf16 bf16x8 __attribute__((ext_vector_type(8)));
typedef float f32x4 __attribute__((ext_vector_type(4)));

__device__ __forceinline__ void atomAdd(float* p, float v) { unsafeAtomicAdd(p, v); }

__device__ __forceinline__ unsigned packrec(unsigned src, float w) {
    __bf16 bw = (__bf16)w;
    unsigned short us = *(unsigned short*)&bw;
    return (src << 16) | (unsigned)us;
}

// W -> transposed bf16; counters zeroed (block 0). 96 blocks.
__global__ __launch_bounds__(256) void init_k(
    const float* __restrict__ W1rel, const float* __restrict__ W1root,
    const float* __restrict__ W2rel, const float* __restrict__ W2root,
    __bf16* __restrict__ W1t, __bf16* __restrict__ W2t,
    int* __restrict__ gcnt, int* __restrict__ ovfcnt,
    float* __restrict__ bnsum, float* __restrict__ bnsq) {
    if (blockIdx.x == 0) {
        int t = threadIdx.x;
        if (t < NB) gcnt[t] = 0;
        if (t == 0) *ovfcnt = 0;
        if (t < 128) { bnsum[t] = 0.f; bnsq[t] = 0.f; }
    }
    int idx = blockIdx.x * 256 + threadIdx.x;
    if (idx < 128 * 128) {
        int n = idx >> 7, k = idx & 127;
        float v = (k < 64) ? W1rel[k * 128 + n] : W1root[(k - 64) * 128 + n];
        W1t[n * 128 + k] = (__bf16)v;
    } else if (idx < 128 * 128 + 64 * 128) {
        int j = idx - 128 * 128;
        int n = j >> 7, k = j & 127;
        float v = (n < 32) ? W2rel[k * 32 + n] : W2root[k * 32 + (n - 32)];
        W2t[n * 128 + k] = (__bf16)v;
    }
}

// Fused: x->bf16 conversion blocks + edge-partition blocks (independent work).
// Record: u32 ((dstloc<<24)|src), u32 w_bits(f32). (src<2^24, dstloc<196)
__global__ __launch_bounds__(256) void partx_k(
    const float* __restrict__ x, __bf16* __restrict__ xb, int xcB,
    const float* __restrict__ ea, const void* __restrict__ ei,
    int* __restrict__ gcnt, uint2* __restrict__ part,
    int* __restrict__ ovfcnt, int4* __restrict__ ovf, int E, int N) {
    __shared__ int s_flag;
    __shared__ int hist[NB];
    __shared__ int gb[NB];
    __shared__ uint2 stage[NB * LCAP];   // 32 KB

    if ((int)blockIdx.x < xcB) {
        int j = blockIdx.x * 256 + threadIdx.x;
        if (j < N * 8) {
            const float4* xs = (const float4*)(x + (size_t)j * 8);
            float4 a = xs[0], b = xs[1];
            bf16x8 v;
            v[0] = (__bf16)a.x; v[1] = (__bf16)a.y; v[2] = (__bf16)a.z; v[3] = (__bf16)a.w;
            v[4] = (__bf16)b.x; v[5] = (__bf16)b.y; v[6] = (__bf16)b.z; v[7] = (__bf16)b.w;
            *(bf16x8*)(xb + (size_t)j * 8) = v;
        }
        return;
    }
    const int pb = blockIdx.x - xcB;

    if (threadIdx.x < 64) {
        const long long* p = (const long long*)ei;
        long long v = p[threadIdx.x & 15];
        int ok = (v >= 0 && v < (long long)N);
        unsigned long long m = __ballot(ok);
        if (threadIdx.x == 0) s_flag = (~m == 0ull) ? 1 : 0;
    }
    for (int i = threadIdx.x; i < NB; i += 256) hist[i] = 0;
    __syncthreads();
    const bool is64 = (s_flag != 0);

    const int base = pb * CHUNK + threadIdx.x * 4;
    int n = E - base; n = n < 0 ? 0 : (n > 4 ? 4 : n);

    int srcs[4], dsts[4]; float wv[4];
    if (n > 0) {
        if (is64) {
            const long long* p = (const long long*)ei;
            if (n == 4 && ((E & 1) == 0)) {
                int4 a0 = *(const int4*)(p + base);
                int4 a1 = *(const int4*)(p + base + 2);
                srcs[0] = a0.x; srcs[1] = a0.z; srcs[2] = a1.x; srcs[3] = a1.z;
                int4 b0 = *(const int4*)(p + E + base);
                int4 b1 = *(const int4*)(p + E + base + 2);
                dsts[0] = b0.x; dsts[1] = b0.z; dsts[2] = b1.x; dsts[3] = b1.z;
            } else {
                for (int k = 0; k < n; k++) { srcs[k] = (int)p[base + k]; dsts[k] = (int)p[E + base + k]; }
            }
        } else {
            const int* p = (const int*)ei;
            if (n == 4 && ((E & 3) == 0)) {
                int4 a = *(const int4*)(p + base);
                srcs[0] = a.x; srcs[1] = a.y; srcs[2] = a.z; srcs[3] = a.w;
                int4 b = *(const int4*)(p + E + base);
                dsts[0] = b.x; dsts[1] = b.y; dsts[2] = b.z; dsts[3] = b.w;
            } else {
                for (int k = 0; k < n; k++) { srcs[k] = p[base + k]; dsts[k] = p[E + base + k]; }
            }
        }
        if (n == 4) {
            float4 w0 = *(const float4*)(ea + base);
            wv[0] = w0.x; wv[1] = w0.y; wv[2] = w0.z; wv[3] = w0.w;
        } else {
            for (int k = 0; k < n; k++) wv[k] = ea[base + k];
        }

        int bk[4], pos[4], loc[4];
#pragma unroll
        for (int k = 0; k < 4; k++) {
            if (k < n) {
                unsigned b = ((unsigned)dsts[k] << 8) / (unsigned)N;
                int r0 = (int)((b * (unsigned)N + 255u) >> 8);
                bk[k] = (int)b;
                loc[k] = dsts[k] - r0;
                pos[k] = atomicAdd(&hist[b], 1);
            }
        }
#pragma unroll
        for (int k = 0; k < 4; k++) {
            if (k < n) {
                unsigned packed = ((unsigned)loc[k] << 24) | (unsigned)srcs[k];
                if (pos[k] < LCAP) {
                    stage[bk[k] * LCAP + pos[k]] = make_uint2(packed, __float_as_uint(wv[k]));
                } else {
                    int g = atomicAdd(&gcnt[bk[k]], 1);
                    if (g < CAPB) {
                        part[(size_t)bk[k] * CAPB + g] = make_uint2(packed, __float_as_uint(wv[k]));
                    } else {
                        int o = atomicAdd(ovfcnt, 1);
                        if (o < OVF_CAP) ovf[o] = make_int4(srcs[k], dsts[k], (int)__float_as_uint(wv[k]), 0);
                    }
                }
            }
        }
    }
    __syncthreads();
    if (threadIdx.x < NB) {
        int h = hist[threadIdx.x]; if (h > LCAP) h = LCAP;
        hist[threadIdx.x] = h;
        gb[threadIdx.x] = h ? atomicAdd(&gcnt[threadIdx.x], h) : 0;
    }
    __syncthreads();
    const int wvi = threadIdx.x >> 6;
    const int sub = (threadIdx.x >> 4) & 3;
    const int f = threadIdx.x & 15;
    for (int round = 0; round < 16; ++round) {
        int b = wvi * 64 + round * 4 + sub;
        int h = hist[b];
        if (f < h) {
            int g = gb[b] + f;
            uint2 r = stage[b * LCAP + f];
            if (g < CAPB) {
                part[(size_t)b * CAPB + g] = r;
            } else {
                int r0 = (b * N + 255) >> 8;
                int dst = r0 + (int)(r.x >> 24);
                int o = atomicAdd(ovfcnt, 1);
                if (o < OVF_CAP) ovf[o] = make_int4((int)(r.x & 0xFFFFFFu), dst, (int)r.y, 0);
            }
        }
    }
}

// Per-bucket: scatter records into per-dst 4B bins in LDS, write out dense.
// 512 threads (8 waves) for latency hiding.
__global__ __launch_bounds__(512) void binscat_k(
    const int* __restrict__ gcnt, const uint2* __restrict__ part,
    unsigned* __restrict__ bins, int* __restrict__ cnt,
    int* __restrict__ ovfcnt, int4* __restrict__ ovf, int N) {
    __shared__ unsigned stage[MAXROWS * CAP];   // 25 KB
    __shared__ int lcnt[MAXROWS];
    const int b = blockIdx.x;
    const int r0 = (b * N + 255) >> 8;
    int r1 = ((b + 1) * N + 255) >> 8; if (r1 > N) r1 = N;
    const int rows = r1 - r0;
    for (int i = threadIdx.x; i < rows; i += 512) lcnt[i] = 0;
    __syncthreads();

    int m = gcnt[b]; if (m > CAPB) m = CAPB;
    const uint2* pb = part + (size_t)b * CAPB;
    for (int i = threadIdx.x; i < m; i += 512) {
        uint2 r = pb[i];
        int d = r.x >> 24;
        unsigned src = r.x & 0xFFFFFFu;
        float w = __uint_as_float(r.y);
        int pos = atomicAdd(&lcnt[d], 1);
        if (pos < CAP) {
            stage[d * CAP + pos] = packrec(src, w);
        } else {
            int o = atomicAdd(ovfcnt, 1);
            if (o < OVF_CAP) ovf[o] = make_int4((int)src, r0 + d, (int)r.y, 0);
        }
    }
    __syncthreads();
    uint4* dst = (uint4*)(bins + (size_t)r0 * CAP);
    const uint4* srcp = (const uint4*)stage;
    for (int i = threadIdx.x; i < rows * (CAP / 4); i += 512) dst[i] = srcp[i];
    for (int i = threadIdx.x; i < rows; i += 512) cnt[r0 + i] = lcnt[i];
}

// agg_bf[row] = bf16(sum w*x_bf[src]); half-wave per edge, ushort2 gathers.
// lane = sub*32 + fp: sub = edge parity, fp = feature pair (2fp, 2fp+1).
__global__ __launch_bounds__(1024) void spmm1_k(
    const __bf16* __restrict__ xb, const int* __restrict__ cntg,
    const unsigned* __restrict__ bins, const int* __restrict__ ovfcnt,
    const int4* __restrict__ ovf, __bf16* __restrict__ aggb, int N) {
    const int lane = threadIdx.x & 63;
    const int sub = lane >> 5;
    const int fp = lane & 31;
    const int row = (int)((blockIdx.x * 1024 + threadIdx.x) >> 6);
    if (row >= N) return;
    int cf = cntg[row];
    int cnt = cf > CAP ? CAP : cf;
    unsigned eg = 0u;
    if (lane < cnt) eg = bins[(size_t)row * CAP + lane];
    float ax = 0.f, ay = 0.f;
    for (int j = 0; j < cnt; j += 8) {
        int ss[4]; float ww[4]; unsigned uv[4];
#pragma unroll
        for (int k = 0; k < 4; k++) {
            int idx = j + 2 * k + sub;
            bool ok = idx < cnt;
            unsigned r = (unsigned)__shfl((int)eg, idx);
            ss[k] = ok ? (int)(r >> 16) : 0;
            ww[k] = ok ? __uint_as_float((r & 0xFFFFu) << 16) : 0.f;
        }
#pragma unroll
        for (int k = 0; k < 4; k++)
            uv[k] = *(const unsigned*)((const char*)xb + (size_t)ss[k] * 128 + fp * 4);
#pragma unroll
        for (int k = 0; k < 4; k++) {
            ax = fmaf(ww[k], __uint_as_float((uv[k] & 0xFFFFu) << 16), ax);
            ay = fmaf(ww[k], __uint_as_float(uv[k] & 0xFFFF0000u), ay);
        }
    }
    if (cf > CAP && sub == 0) {   // rare heavy row; only sub0 (combined below)
        int nv = *ovfcnt; if (nv > OVF_CAP) nv = OVF_CAP;
        for (int i = 0; i < nv; i++) {
            int4 t = ovf[i];
            if (t.y == row) {
                float w = __uint_as_float((unsigned)t.z);
                unsigned u = *(const unsigned*)((const char*)xb + (size_t)t.x * 128 + fp * 4);
                ax = fmaf(w, __uint_as_float((u & 0xFFFFu) << 16), ax);
                ay = fmaf(w, __uint_as_float(u & 0xFFFF0000u), ay);
            }
        }
    }
    ax += __shfl_xor(ax, 32);
    ay += __shfl_xor(ay, 32);
    if (sub == 0) {
        __bf16 b0 = (__bf16)ax, b1 = (__bf16)ay;
        unsigned pack = (unsigned)*(unsigned short*)&b0 |
                        ((unsigned)*(unsigned short*)&b1 << 16);
        *(unsigned*)((char*)aggb + (size_t)row * 128 + fp * 4) = pack;
    }
}

// MFMA gemm1: h_bf = bf16([agg|x] @ W1t^T + b1). W1t in LDS (swizzled);
// 2 row-tiles/wave; BN partials -> 256 f32 atomics.
__global__ __launch_bounds__(256) void gemm1_k(
    const __bf16* __restrict__ aggb, const __bf16* __restrict__ xb,
    const __bf16* __restrict__ W1t, const float* __restrict__ b1,
    __bf16* __restrict__ hb, float* __restrict__ bnsum, float* __restrict__ bnsq,
    int N) {
    __shared__ char Wl[128 * 256];        // 32 KB, swizzled
    __shared__ float redS[4][128];
    __shared__ float redQ[4][128];
    const int t = threadIdx.x;
    for (int i = t; i < 2048; i += 256) {
        int byte = i * 16;
        int row = byte >> 8;
        int sw = byte ^ ((row & 7) << 4);
        *(uint4*)(Wl + sw) = *(const uint4*)((const char*)W1t + byte);
    }

    const int lane = t & 63;
    const int w = t >> 6;
    const int rrow = lane & 15;
    const int q = lane >> 4;
    const int rowbase = blockIdx.x * 128 + w * 32;
    const int ar0 = rowbase + rrow;
    const int ar1 = rowbase + 16 + rrow;
    const int ar0c = (ar0 < N) ? ar0 : (N - 1);
    const int ar1c = (ar1 < N) ? ar1 : (N - 1);

    f32x4 acc0[8], acc1[8];
#pragma unroll
    for (int cb = 0; cb < 8; cb++) {
        acc0[cb][0] = 0.f; acc0[cb][1] = 0.f; acc0[cb][2] = 0.f; acc0[cb][3] = 0.f;
        acc1[cb][0] = 0.f; acc1[cb][1] = 0.f; acc1[cb][2] = 0.f; acc1[cb][3] = 0.f;
    }
    __syncthreads();

#pragma unroll
    for (int ks = 0; ks < 4; ks++) {
        const int koff = (ks & 1) * 32 + q * 8;
        const __bf16* base = (ks < 2) ? aggb : xb;
        bf16x8 a0 = *(const bf16x8*)(base + (size_t)ar0c * 64 + koff);
        bf16x8 a1 = *(const bf16x8*)(base + (size_t)ar1c * 64 + koff);
#pragma unroll
        for (int cb = 0; cb < 8; cb++) {
            int byte = (cb * 16 + rrow) * 256 + ks * 64 + q * 16;
            byte ^= ((rrow & 7) << 4);
            bf16x8 b = *(const bf16x8*)(Wl + byte);
            acc0[cb] = __builtin_amdgcn_mfma_f32_16x16x32_bf16(a0, b, acc0[cb], 0, 0, 0);
            acc1[cb] = __builtin_amdgcn_mfma_f32_16x16x32_bf16(a1, b, acc1[cb], 0, 0, 0);
        }
    }

    float s[8], qs[8];
#pragma unroll
    for (int cb = 0; cb < 8; cb++) {
        const int col = cb * 16 + rrow;
        const float bc = b1[col];
        float ls = 0.f, lq = 0.f;
#pragma unroll
        for (int r = 0; r < 4; r++) {
            int rr0 = rowbase + 4 * q + r;
            if (rr0 < N) {
                float v = acc0[cb][r] + bc;
                hb[(size_t)rr0 * 128 + col] = (__bf16)v;
                ls += v; lq += v * v;
            }
            int rr1 = rowbase + 16 + 4 * q + r;
            if (rr1 < N) {
                float v = acc1[cb][r] + bc;
                hb[(size_t)rr1 * 128 + col] = (__bf16)v;
                ls += v; lq += v * v;
            }
        }
        s[cb] = ls; qs[cb] = lq;
    }
#pragma unroll
    for (int cb = 0; cb < 8; cb++) {
        s[cb] += __shfl_xor(s[cb], 16);  s[cb] += __shfl_xor(s[cb], 32);
        qs[cb] += __shfl_xor(qs[cb], 16); qs[cb] += __shfl_xor(qs[cb], 32);
    }
    if (q == 0) {
#pragma unroll
        for (int cb = 0; cb < 8; cb++) {
            redS[w][cb * 16 + rrow] = s[cb];
            redQ[w][cb * 16 + rrow] = qs[cb];
        }
    }
    __syncthreads();
    if (t < 128) {
        atomAdd(&bnsum[t], redS[0][t] + redS[1][t] + redS[2][t] + redS[3][t]);
    } else {
        int c = t - 128;
        atomAdd(&bnsq[c], redQ[0][c] + redQ[1][c] + redQ[2][c] + redQ[3][c]);
    }
}

// MFMA gemm2: per-block BN finalize; act = tanh(h*sc+sh) fused;
// W2t in LDS (swizzled); 2 row-tiles/wave. cols 0..31 -> y2_bf, 32..63 -> out.
__global__ __launch_bounds__(256) void gemm2_k(
    const __bf16* __restrict__ hb, const float* __restrict__ bnsum,
    const float* __restrict__ bnsq, const float* __restrict__ gamma,
    const float* __restrict__ beta, const __bf16* __restrict__ W2t,
    const float* __restrict__ b2, __bf16* __restrict__ y2b,
    float* __restrict__ out, int N) {
    __shared__ char Wl[64 * 256];         // 16 KB, swizzled
    __shared__ float scs[128], shs[128];
    const int t = threadIdx.x;
    for (int i = t; i < 1024; i += 256) {
        int byte = i * 16;
        int row = byte >> 8;
        int sw = byte ^ ((row & 7) << 4);
        *(uint4*)(Wl + sw) = *(const uint4*)((const char*)W2t + byte);
    }
    if (t < 128) {
        float inv = 1.0f / (float)N;
        float mean = bnsum[t] * inv;
        float var = bnsq[t] * inv - mean * mean;
        if (var < 0.f) var = 0.f;
        float sc = gamma[t] * rsqrtf(var + 1e-5f);
        scs[t] = sc;
        shs[t] = beta[t] - mean * sc;
    }

    const int lane = t & 63;
    const int w = t >> 6;
    const int rrow = lane & 15;
    const int q = lane >> 4;
    const int rowbase = blockIdx.x * 128 + w * 32;
    const int ar0 = rowbase + rrow;
    const int ar1 = rowbase + 16 + rrow;
    const int ar0c = (ar0 < N) ? ar0 : (N - 1);
    const int ar1c = (ar1 < N) ? ar1 : (N - 1);

    f32x4 acc0[4], acc1[4];
#pragma unroll
    for (int cb = 0; cb < 4; cb++) {
        acc0[cb][0] = 0.f; acc0[cb][1] = 0.f; acc0[cb][2] = 0.f; acc0[cb][3] = 0.f;
        acc1[cb][0] = 0.f; acc1[cb][1] = 0.f; acc1[cb][2] = 0.f; acc1[cb][3] = 0.f;
    }
    __syncthreads();

#pragma unroll
    for (int ks = 0; ks < 4; ks++) {
        const int k0 = ks * 32 + q * 8;
        bf16x8 hv0 = *(const bf16x8*)(hb + (size_t)ar0c * 128 + k0);
        bf16x8 hv1 = *(const bf16x8*)(hb + (size_t)ar1c * 128 + k0);
        bf16x8 a0, a1;
#pragma unroll
        for (int i = 0; i < 8; i++) {
            float sc = scs[k0 + i], sh = shs[k0 + i];
            a0[i] = (__bf16)tanhf(fmaf((float)hv0[i], sc, sh));
            a1[i] = (__bf16)tanhf(fmaf((float)hv1[i], sc, sh));
        }
#pragma unroll
        for (int cb = 0; cb < 4; cb++) {
            int byte = (cb * 16 + rrow) * 256 + ks * 64 + q * 16;
            byte ^= ((rrow & 7) << 4);
            bf16x8 b = *(const bf16x8*)(Wl + byte);
            acc0[cb] = __builtin_amdgcn_mfma_f32_16x16x32_bf16(a0, b, acc0[cb], 0, 0, 0);
            acc1[cb] = __builtin_amdgcn_mfma_f32_16x16x32_bf16(a1, b, acc1[cb], 0, 0, 0);
        }
    }

#pragma unroll
    for (int cb = 0; cb < 4; cb++) {
        const int col = cb * 16 + rrow;
        const bool isRel = (col < 32);
        const int cc = isRel ? col : (col - 32);
        const float bc = isRel ? 0.f : b2[cc];
#pragma unroll
        for (int r = 0; r < 4; r++) {
            int rr0 = rowbase + 4 * q + r;
            if (rr0 < N) {
                if (isRel) y2b[(size_t)rr0 * 32 + cc] = (__bf16)acc0[cb][r];
                else       out[(size_t)rr0 * 32 + cc] = acc0[cb][r] + bc;
            }
            int rr1 = rowbase + 16 + 4 * q + r;
            if (rr1 < N) {
                if (isRel) y2b[(size_t)rr1 * 32 + cc] = (__bf16)acc1[cb][r];
                else       out[(size_t)rr1 * 32 + cc] = acc1[cb][r] + bc;
            }
        }
    }
}

// out[row] += sum w*y2_bf[src]; quarter-wave per edge (16 lanes x ushort2
// = full 64B y2 row), 4 edges/wave-iter.
__global__ __launch_bounds__(1024) void spmm2_k(
    const __bf16* __restrict__ y2b, const int* __restrict__ cntg,
    const unsigned* __restrict__ bins, const int* __restrict__ ovfcnt,
    const int4* __restrict__ ovf, float* __restrict__ out, int N) {
    const int lane = threadIdx.x & 63;
    const int qs = lane >> 4;       // edge slot 0..3
    const int fp = lane & 15;       // feature pair (2fp, 2fp+1)
    const int row = (int)((blockIdx.x * 1024 + threadIdx.x) >> 6);
    if (row >= N) return;
    int cf = cntg[row];
    int cnt = cf > CAP ? CAP : cf;
    unsigned eg = 0u;
    if (lane < cnt) eg = bins[(size_t)row * CAP + lane];
    float ax = 0.f, ay = 0.f;
    for (int j = 0; j < cnt; j += 8) {
        int ss[2]; float ww[2]; unsigned uv[2];
#pragma unroll
        for (int k = 0; k < 2; k++) {
            int idx = j + 4 * k + qs;
            bool ok = idx < cnt;
            unsigned r = (unsigned)__shfl((int)eg, idx);
            ss[k] = ok ? (int)(r >> 16) : 0;
            ww[k] = ok ? __uint_as_float((r & 0xFFFFu) << 16) : 0.f;
        }
#pragma unroll
        for (int k = 0; k < 2; k++)
            uv[k] = *(const unsigned*)((const char*)y2b + (size_t)ss[k] * 64 + fp * 4);
#pragma unroll
        for (int k = 0; k < 2; k++) {
            ax = fmaf(ww[k], __uint_as_float((uv[k] & 0xFFFFu) << 16), ax);
            ay = fmaf(ww[k], __uint_as_float(uv[k] & 0xFFFF0000u), ay);
        }
    }
    if (cf > CAP && qs == 0) {   // rare heavy row; only qs0 (combined below)
        int nv = *ovfcnt; if (nv > OVF_CAP) nv = OVF_CAP;
        for (int i = 0; i < nv; i++) {
            int4 t = ovf[i];
            if (t.y == row) {
                float w = __uint_as_float((unsigned)t.z);
                unsigned u = *(const unsigned*)((const char*)y2b + (size_t)t.x * 64 + fp * 4);
                ax = fmaf(w, __uint_as_float((u & 0xFFFFu) << 16), ax);
                ay = fmaf(w, __uint_as_float(u & 0xFFFF0000u), ay);
            }
        }
    }
    ax += __shfl_xor(ax, 16); ax += __shfl_xor(ax, 32);
    ay += __shfl_xor(ay, 16); ay += __shfl_xor(ay, 32);
    if (qs == 0) {
        float2* p = (float2*)((char*)out + (size_t)row * 128 + fp * 8);
        float2 c = *p;
        c.x += ax; c.y += ay;
        *p = c;
    }
}

extern "C" void kernel_launch(void* const* d_in, const int* in_sizes, int n_in,
                              void* d_out, int out_size, void* d_ws, size_t ws_size,
                              hipStream_t stream) {
    const float* x      = (const float*)d_in[0];
    const float* ea     = (const float*)d_in[1];
    const float* W1rel  = (const float*)d_in[2];
    const float* b1     = (const float*)d_in[3];
    const float* W1root = (const float*)d_in[4];
    const float* gamma  = (const float*)d_in[5];
    const float* beta   = (const float*)d_in[6];
    const float* W2rel  = (const float*)d_in[7];
    const float* b2     = (const float*)d_in[8];
    const float* W2root = (const float*)d_in[9];
    const void*  ei     = d_in[10];

    const int N = in_sizes[0] / 64;   // 50000
    const int E = in_sizes[1];        // 800000
    const int nbg = (N + 127) / 128;  // gemm blocks (128 rows each)

    char* ws = (char*)d_ws;
    size_t off = 0;
    int*      gcnt    = (int*)     (ws + off); off += NB * 4;
    int*      ovfcnt  = (int*)     (ws + off); off += 256;
    float*    bnsum   = (float*)   (ws + off); off += 512;
    float*    bnsq    = (float*)   (ws + off); off += 512;
    int*      cnt     = (int*)     (ws + off); off += ((size_t)N * 4 + 255) & ~255ull;
    __bf16*   xb      = (__bf16*)  (ws + off); off += (size_t)N * 64 * 2;     // 6.4 MB
    __bf16*   aggb    = (__bf16*)  (ws + off); off += (size_t)N * 64 * 2;     // 6.4 MB
    __bf16*   hb      = (__bf16*)  (ws + off); off += (size_t)N * 128 * 2;    // 12.8 MB
    __bf16*   y2b     = (__bf16*)  (ws + off); off += (size_t)N * 32 * 2;     // 3.2 MB
    uint2*    part    = (uint2*)   (ws + off); off += (size_t)NB * CAPB * 8;  // 8.4 MB
    unsigned* bins    = (unsigned*)(ws + off); off += (size_t)N * CAP * 4;    // 6.4 MB
    int4*     ovf     = (int4*)    (ws + off); off += (size_t)OVF_CAP * 16;   // 2 MB
    __bf16*   W1t     = (__bf16*)  (ws + off); off += 128 * 128 * 2;
    __bf16*   W2t     = (__bf16*)  (ws + off); off += 64 * 128 * 2;

    init_k<<<96, 256, 0, stream>>>(W1rel, W1root, W2rel, W2root, W1t, W2t,
                                   gcnt, ovfcnt, bnsum, bnsq);
    const int xcB = (N * 8 + 255) / 256;
    const int partB = (E + CHUNK - 1) / CHUNK;
    partx_k<<<xcB + partB, 256, 0, stream>>>(x, xb, xcB, ea, ei, gcnt, part,
                                             ovfcnt, ovf, E, N);
    binscat_k<<<NB, 512, 0, stream>>>(gcnt, part, bins, cnt, ovfcnt, ovf, N);
    const int rowBlocks = (N * 64 + 1023) / 1024;
    spmm1_k<<<rowBlocks, 1024, 0, stream>>>(xb, cnt, bins, ovfcnt, ovf, aggb, N);
    gemm1_k<<<nbg, 256, 0, stream>>>(aggb, xb, W1t, b1, hb, bnsum, bnsq, N);
    gemm2_k<<<nbg, 256, 0, stream>>>(hb, bnsum, bnsq, gamma, beta, W2t, b2, y2b,
                                     (float*)d_out, N);
    spmm2_k<<<rowBlocks, 1024, 0, stream>>>(y2b, cnt, bins, ovfcnt, ovf, (float*)d_out, N);
}

// Round 14
// 112.455 us; speedup vs baseline: 1.0530x; 1.0530x over previous
//
#include <hip/hip_runtime.h>
#include <hip/hip_bf16.h>

// ---------------------------------------------------------------------------
// GCN 2-layer + BN + tanh. All dense streams bf16 (f32 accum).
//   init_k:    W -> bf16 transposed; zero-inits counters. (tiny)
//   partx_k:   [blocks 0..xcB)   x -> bf16 (BW-bound)
//              [blocks xcB..end) partition E edges into NB=256 dst-buckets
//              (coalesced 8B recs; staging spills -> direct bucket slot).
//   binscat_k: per-bucket LDS scatter -> per-dst 4B bins (src:u16|w:bf16)+cnt.
//   spmm1_k:   one wave/row, HALF-WAVE per edge (ushort2 gathers):
//              agg_bf = bf16(sum w*x_bf[src]); ovf scan inline.
//   gemm1_k:   h_bf = bf16([agg|x] @ [W1rel;W1root] + b1) (MFMA, W in LDS
//              swizzled, 2 row-tiles/wave); BN partials -> f32 atomics.
//   gemm2_k:   per-block BN finalize; act=tanh fused; y2_bf=act@W2rel,
//              out=act@W2root+b2 (f32).
//   spmm2_k:   one wave/row, QUARTER-WAVE per edge: out += sum w*y2_bf[src].
// MFMA 16x16x32 bf16 lane maps (m89-verified D):
//   A: row=lane&15, k=8*(lane>>4)+i ; B: col=lane&15 (Wt[n][k]) ;
//   D: col=lane&15, row=4*(lane>>4)+reg
// LDS W swizzle: byte ^= (row&7)<<4  (256B per k-row)
// NOTE: 4B bin records assume N <= 65536 (harness N=50000).
// R13 lesson: more blocks/threads per stage regressed (per-block fixed costs:
// histogram zero + copy-out rounds dominate). This is the R12 configuration.
// ---------------------------------------------------------------------------

#define NB 256
#define CAPB 4096
#define LCAP 16
#define CHUNK 2048
#define CAP 32
#define MAXROWS 196
#define OVF_CAP 131072

typedef __bf16 bf16x8 __attribute__((ext_vector_type(8)));
typedef float f32x4 __attribute__((ext_vector_type(4)));

__device__ __forceinline__ void atomAdd(float* p, float v) { unsafeAtomicAdd(p, v); }

__device__ __forceinline__ unsigned packrec(unsigned src, float w) {
    __bf16 bw = (__bf16)w;
    unsigned short us = *(unsigned short*)&bw;
    return (src << 16) | (unsigned)us;
}

// W -> transposed bf16; counters zeroed (block 0). 96 blocks.
__global__ __launch_bounds__(256) void init_k(
    const float* __restrict__ W1rel, const float* __restrict__ W1root,
    const float* __restrict__ W2rel, const float* __restrict__ W2root,
    __bf16* __restrict__ W1t, __bf16* __restrict__ W2t,
    int* __restrict__ gcnt, int* __restrict__ ovfcnt,
    float* __restrict__ bnsum, float* __restrict__ bnsq) {
    if (blockIdx.x == 0) {
        int t = threadIdx.x;
        if (t < NB) gcnt[t] = 0;
        if (t == 0) *ovfcnt = 0;
        if (t < 128) { bnsum[t] = 0.f; bnsq[t] = 0.f; }
    }
    int idx = blockIdx.x * 256 + threadIdx.x;
    if (idx < 128 * 128) {
        int n = idx >> 7, k = idx & 127;
        float v = (k < 64) ? W1rel[k * 128 + n] : W1root[(k - 64) * 128 + n];
        W1t[n * 128 + k] = (__bf16)v;
    } else if (idx < 128 * 128 + 64 * 128) {
        int j = idx - 128 * 128;
        int n = j >> 7, k = j & 127;
        float v = (n < 32) ? W2rel[k * 32 + n] : W2root[k * 32 + (n - 32)];
        W2t[n * 128 + k] = (__bf16)v;
    }
}

// Fused: x->bf16 conversion blocks + edge-partition blocks (independent work).
// Record: u32 ((dstloc<<24)|src), u32 w_bits(f32). (src<2^24, dstloc<196)
__global__ __launch_bounds__(256) void partx_k(
    const float* __restrict__ x, __bf16* __restrict__ xb, int xcB,
    const float* __restrict__ ea, const void* __restrict__ ei,
    int* __restrict__ gcnt, uint2* __restrict__ part,
    int* __restrict__ ovfcnt, int4* __restrict__ ovf, int E, int N) {
    __shared__ int s_flag;
    __shared__ int hist[NB];
    __shared__ int gb[NB];
    __shared__ uint2 stage[NB * LCAP];   // 32 KB

    if ((int)blockIdx.x < xcB) {
        int j = blockIdx.x * 256 + threadIdx.x;
        if (j < N * 8) {
            const float4* xs = (const float4*)(x + (size_t)j * 8);
            float4 a = xs[0], b = xs[1];
            bf16x8 v;
            v[0] = (__bf16)a.x; v[1] = (__bf16)a.y; v[2] = (__bf16)a.z; v[3] = (__bf16)a.w;
            v[4] = (__bf16)b.x; v[5] = (__bf16)b.y; v[6] = (__bf16)b.z; v[7] = (__bf16)b.w;
            *(bf16x8*)(xb + (size_t)j * 8) = v;
        }
        return;
    }
    const int pb = blockIdx.x - xcB;

    if (threadIdx.x < 64) {
        const long long* p = (const long long*)ei;
        long long v = p[threadIdx.x & 15];
        int ok = (v >= 0 && v < (long long)N);
        unsigned long long m = __ballot(ok);
        if (threadIdx.x == 0) s_flag = (~m == 0ull) ? 1 : 0;
    }
    for (int i = threadIdx.x; i < NB; i += 256) hist[i] = 0;
    __syncthreads();
    const bool is64 = (s_flag != 0);

    const int base = pb * CHUNK + threadIdx.x * 8;
    int n = E - base; n = n < 0 ? 0 : (n > 8 ? 8 : n);

    int srcs[8], dsts[8]; float wv[8];
    if (n > 0) {
        if (is64) {
            const long long* p = (const long long*)ei;
            if (n == 8 && ((E & 1) == 0)) {
#pragma unroll
                for (int k = 0; k < 4; k++) {
                    int4 a = *(const int4*)(p + base + 2 * k);
                    srcs[2 * k] = a.x; srcs[2 * k + 1] = a.z;
                }
#pragma unroll
                for (int k = 0; k < 4; k++) {
                    int4 b = *(const int4*)(p + E + base + 2 * k);
                    dsts[2 * k] = b.x; dsts[2 * k + 1] = b.z;
                }
            } else {
                for (int k = 0; k < n; k++) { srcs[k] = (int)p[base + k]; dsts[k] = (int)p[E + base + k]; }
            }
        } else {
            const int* p = (const int*)ei;
            if (n == 8 && ((E & 3) == 0)) {
                int4 a0 = *(const int4*)(p + base);
                int4 a1 = *(const int4*)(p + base + 4);
                srcs[0] = a0.x; srcs[1] = a0.y; srcs[2] = a0.z; srcs[3] = a0.w;
                srcs[4] = a1.x; srcs[5] = a1.y; srcs[6] = a1.z; srcs[7] = a1.w;
                int4 b0 = *(const int4*)(p + E + base);
                int4 b1 = *(const int4*)(p + E + base + 4);
                dsts[0] = b0.x; dsts[1] = b0.y; dsts[2] = b0.z; dsts[3] = b0.w;
                dsts[4] = b1.x; dsts[5] = b1.y; dsts[6] = b1.z; dsts[7] = b1.w;
            } else {
                for (int k = 0; k < n; k++) { srcs[k] = p[base + k]; dsts[k] = p[E + base + k]; }
            }
        }
        if (n == 8) {
            float4 w0 = *(const float4*)(ea + base);
            float4 w1 = *(const float4*)(ea + base + 4);
            wv[0] = w0.x; wv[1] = w0.y; wv[2] = w0.z; wv[3] = w0.w;
            wv[4] = w1.x; wv[5] = w1.y; wv[6] = w1.z; wv[7] = w1.w;
        } else {
            for (int k = 0; k < n; k++) wv[k] = ea[base + k];
        }

        int bk[8], pos[8], loc[8];
#pragma unroll
        for (int k = 0; k < 8; k++) {
            if (k < n) {
                unsigned b = ((unsigned)dsts[k] << 8) / (unsigned)N;
                int r0 = (int)((b * (unsigned)N + 255u) >> 8);
                bk[k] = (int)b;
                loc[k] = dsts[k] - r0;
                pos[k] = atomicAdd(&hist[b], 1);
            }
        }
#pragma unroll
        for (int k = 0; k < 8; k++) {
            if (k < n) {
                unsigned packed = ((unsigned)loc[k] << 24) | (unsigned)srcs[k];
                if (pos[k] < LCAP) {
                    stage[bk[k] * LCAP + pos[k]] = make_uint2(packed, __float_as_uint(wv[k]));
                } else {
                    int g = atomicAdd(&gcnt[bk[k]], 1);
                    if (g < CAPB) {
                        part[(size_t)bk[k] * CAPB + g] = make_uint2(packed, __float_as_uint(wv[k]));
                    } else {
                        int o = atomicAdd(ovfcnt, 1);
                        if (o < OVF_CAP) ovf[o] = make_int4(srcs[k], dsts[k], (int)__float_as_uint(wv[k]), 0);
                    }
                }
            }
        }
    }
    __syncthreads();
    if (threadIdx.x < NB) {
        int h = hist[threadIdx.x]; if (h > LCAP) h = LCAP;
        hist[threadIdx.x] = h;
        gb[threadIdx.x] = h ? atomicAdd(&gcnt[threadIdx.x], h) : 0;
    }
    __syncthreads();
    const int wvi = threadIdx.x >> 6;
    const int sub = (threadIdx.x >> 4) & 3;
    const int f = threadIdx.x & 15;
    for (int round = 0; round < 16; ++round) {
        int b = wvi * 64 + round * 4 + sub;
        int h = hist[b];
        if (f < h) {
            int g = gb[b] + f;
            uint2 r = stage[b * LCAP + f];
            if (g < CAPB) {
                part[(size_t)b * CAPB + g] = r;
            } else {
                int r0 = (b * N + 255) >> 8;
                int dst = r0 + (int)(r.x >> 24);
                int o = atomicAdd(ovfcnt, 1);
                if (o < OVF_CAP) ovf[o] = make_int4((int)(r.x & 0xFFFFFFu), dst, (int)r.y, 0);
            }
        }
    }
}

// Per-bucket: scatter records into per-dst 4B bins in LDS, write out dense.
__global__ __launch_bounds__(256) void binscat_k(
    const int* __restrict__ gcnt, const uint2* __restrict__ part,
    unsigned* __restrict__ bins, int* __restrict__ cnt,
    int* __restrict__ ovfcnt, int4* __restrict__ ovf, int N) {
    __shared__ unsigned stage[MAXROWS * CAP];   // 25 KB
    __shared__ int lcnt[MAXROWS];
    const int b = blockIdx.x;
    const int r0 = (b * N + 255) >> 8;
    int r1 = ((b + 1) * N + 255) >> 8; if (r1 > N) r1 = N;
    const int rows = r1 - r0;
    for (int i = threadIdx.x; i < rows; i += 256) lcnt[i] = 0;
    __syncthreads();

    int m = gcnt[b]; if (m > CAPB) m = CAPB;
    const uint2* pb = part + (size_t)b * CAPB;
    for (int i = threadIdx.x; i < m; i += 256) {
        uint2 r = pb[i];
        int d = r.x >> 24;
        unsigned src = r.x & 0xFFFFFFu;
        float w = __uint_as_float(r.y);
        int pos = atomicAdd(&lcnt[d], 1);
        if (pos < CAP) {
            stage[d * CAP + pos] = packrec(src, w);
        } else {
            int o = atomicAdd(ovfcnt, 1);
            if (o < OVF_CAP) ovf[o] = make_int4((int)src, r0 + d, (int)r.y, 0);
        }
    }
    __syncthreads();
    uint4* dst = (uint4*)(bins + (size_t)r0 * CAP);
    const uint4* srcp = (const uint4*)stage;
    for (int i = threadIdx.x; i < rows * (CAP / 4); i += 256) dst[i] = srcp[i];
    for (int i = threadIdx.x; i < rows; i += 256) cnt[r0 + i] = lcnt[i];
}

// agg_bf[row] = bf16(sum w*x_bf[src]); half-wave per edge, ushort2 gathers.
// lane = sub*32 + fp: sub = edge parity, fp = feature pair (2fp, 2fp+1).
__global__ __launch_bounds__(256) void spmm1_k(
    const __bf16* __restrict__ xb, const int* __restrict__ cntg,
    const unsigned* __restrict__ bins, const int* __restrict__ ovfcnt,
    const int4* __restrict__ ovf, __bf16* __restrict__ aggb, int N) {
    const int lane = threadIdx.x & 63;
    const int sub = lane >> 5;
    const int fp = lane & 31;
    const int row = (blockIdx.x * 256 + threadIdx.x) >> 6;
    if (row >= N) return;
    int cf = cntg[row];
    int cnt = cf > CAP ? CAP : cf;
    unsigned eg = 0u;
    if (lane < cnt) eg = bins[(size_t)row * CAP + lane];
    float ax = 0.f, ay = 0.f;
    for (int j = 0; j < cnt; j += 8) {
        int ss[4]; float ww[4]; unsigned uv[4];
#pragma unroll
        for (int k = 0; k < 4; k++) {
            int idx = j + 2 * k + sub;
            bool ok = idx < cnt;
            unsigned r = (unsigned)__shfl((int)eg, idx);
            ss[k] = ok ? (int)(r >> 16) : 0;
            ww[k] = ok ? __uint_as_float((r & 0xFFFFu) << 16) : 0.f;
        }
#pragma unroll
        for (int k = 0; k < 4; k++)
            uv[k] = *(const unsigned*)((const char*)xb + (size_t)ss[k] * 128 + fp * 4);
#pragma unroll
        for (int k = 0; k < 4; k++) {
            ax = fmaf(ww[k], __uint_as_float((uv[k] & 0xFFFFu) << 16), ax);
            ay = fmaf(ww[k], __uint_as_float(uv[k] & 0xFFFF0000u), ay);
        }
    }
    if (cf > CAP && sub == 0) {   // rare heavy row; only sub0 (combined below)
        int nv = *ovfcnt; if (nv > OVF_CAP) nv = OVF_CAP;
        for (int i = 0; i < nv; i++) {
            int4 t = ovf[i];
            if (t.y == row) {
                float w = __uint_as_float((unsigned)t.z);
                unsigned u = *(const unsigned*)((const char*)xb + (size_t)t.x * 128 + fp * 4);
                ax = fmaf(w, __uint_as_float((u & 0xFFFFu) << 16), ax);
                ay = fmaf(w, __uint_as_float(u & 0xFFFF0000u), ay);
            }
        }
    }
    ax += __shfl_xor(ax, 32);
    ay += __shfl_xor(ay, 32);
    if (sub == 0) {
        __bf16 b0 = (__bf16)ax, b1 = (__bf16)ay;
        unsigned pack = (unsigned)*(unsigned short*)&b0 |
                        ((unsigned)*(unsigned short*)&b1 << 16);
        *(unsigned*)((char*)aggb + (size_t)row * 128 + fp * 4) = pack;
    }
}

// MFMA gemm1: h_bf = bf16([agg|x] @ W1t^T + b1). W1t in LDS (swizzled);
// 2 row-tiles/wave; BN partials -> 256 f32 atomics.
__global__ __launch_bounds__(256) void gemm1_k(
    const __bf16* __restrict__ aggb, const __bf16* __restrict__ xb,
    const __bf16* __restrict__ W1t, const float* __restrict__ b1,
    __bf16* __restrict__ hb, float* __restrict__ bnsum, float* __restrict__ bnsq,
    int N) {
    __shared__ char Wl[128 * 256];        // 32 KB, swizzled
    __shared__ float redS[4][128];
    __shared__ float redQ[4][128];
    const int t = threadIdx.x;
    for (int i = t; i < 2048; i += 256) {
        int byte = i * 16;
        int row = byte >> 8;
        int sw = byte ^ ((row & 7) << 4);
        *(uint4*)(Wl + sw) = *(const uint4*)((const char*)W1t + byte);
    }

    const int lane = t & 63;
    const int w = t >> 6;
    const int rrow = lane & 15;
    const int q = lane >> 4;
    const int rowbase = blockIdx.x * 128 + w * 32;
    const int ar0 = rowbase + rrow;
    const int ar1 = rowbase + 16 + rrow;
    const int ar0c = (ar0 < N) ? ar0 : (N - 1);
    const int ar1c = (ar1 < N) ? ar1 : (N - 1);

    f32x4 acc0[8], acc1[8];
#pragma unroll
    for (int cb = 0; cb < 8; cb++) {
        acc0[cb][0] = 0.f; acc0[cb][1] = 0.f; acc0[cb][2] = 0.f; acc0[cb][3] = 0.f;
        acc1[cb][0] = 0.f; acc1[cb][1] = 0.f; acc1[cb][2] = 0.f; acc1[cb][3] = 0.f;
    }
    __syncthreads();

#pragma unroll
    for (int ks = 0; ks < 4; ks++) {
        const int koff = (ks & 1) * 32 + q * 8;
        const __bf16* base = (ks < 2) ? aggb : xb;
        bf16x8 a0 = *(const bf16x8*)(base + (size_t)ar0c * 64 + koff);
        bf16x8 a1 = *(const bf16x8*)(base + (size_t)ar1c * 64 + koff);
#pragma unroll
        for (int cb = 0; cb < 8; cb++) {
            int byte = (cb * 16 + rrow) * 256 + ks * 64 + q * 16;
            byte ^= ((rrow & 7) << 4);
            bf16x8 b = *(const bf16x8*)(Wl + byte);
            acc0[cb] = __builtin_amdgcn_mfma_f32_16x16x32_bf16(a0, b, acc0[cb], 0, 0, 0);
            acc1[cb] = __builtin_amdgcn_mfma_f32_16x16x32_bf16(a1, b, acc1[cb], 0, 0, 0);
        }
    }

    float s[8], qs[8];
#pragma unroll
    for (int cb = 0; cb < 8; cb++) {
        const int col = cb * 16 + rrow;
        const float bc = b1[col];
        float ls = 0.f, lq = 0.f;
#pragma unroll
        for (int r = 0; r < 4; r++) {
            int rr0 = rowbase + 4 * q + r;
            if (rr0 < N) {
                float v = acc0[cb][r] + bc;
                hb[(size_t)rr0 * 128 + col] = (__bf16)v;
                ls += v; lq += v * v;
            }
            int rr1 = rowbase + 16 + 4 * q + r;
            if (rr1 < N) {
                float v = acc1[cb][r] + bc;
                hb[(size_t)rr1 * 128 + col] = (__bf16)v;
                ls += v; lq += v * v;
            }
        }
        s[cb] = ls; qs[cb] = lq;
    }
#pragma unroll
    for (int cb = 0; cb < 8; cb++) {
        s[cb] += __shfl_xor(s[cb], 16);  s[cb] += __shfl_xor(s[cb], 32);
        qs[cb] += __shfl_xor(qs[cb], 16); qs[cb] += __shfl_xor(qs[cb], 32);
    }
    if (q == 0) {
#pragma unroll
        for (int cb = 0; cb < 8; cb++) {
            redS[w][cb * 16 + rrow] = s[cb];
            redQ[w][cb * 16 + rrow] = qs[cb];
        }
    }
    __syncthreads();
    if (t < 128) {
        atomAdd(&bnsum[t], redS[0][t] + redS[1][t] + redS[2][t] + redS[3][t]);
    } else {
        int c = t - 128;
        atomAdd(&bnsq[c], redQ[0][c] + redQ[1][c] + redQ[2][c] + redQ[3][c]);
    }
}

// MFMA gemm2: per-block BN finalize; act = tanh(h*sc+sh) fused;
// W2t in LDS (swizzled); 2 row-tiles/wave. cols 0..31 -> y2_bf, 32..63 -> out.
__global__ __launch_bounds__(256) void gemm2_k(
    const __bf16* __restrict__ hb, const float* __restrict__ bnsum,
    const float* __restrict__ bnsq, const float* __restrict__ gamma,
    const float* __restrict__ beta, const __bf16* __restrict__ W2t,
    const float* __restrict__ b2, __bf16* __restrict__ y2b,
    float* __restrict__ out, int N) {
    __shared__ char Wl[64 * 256];         // 16 KB, swizzled
    __shared__ float scs[128], shs[128];
    const int t = threadIdx.x;
    for (int i = t; i < 1024; i += 256) {
        int byte = i * 16;
        int row = byte >> 8;
        int sw = byte ^ ((row & 7) << 4);
        *(uint4*)(Wl + sw) = *(const uint4*)((const char*)W2t + byte);
    }
    if (t < 128) {
        float inv = 1.0f / (float)N;
        float mean = bnsum[t] * inv;
        float var = bnsq[t] * inv - mean * mean;
        if (var < 0.f) var = 0.f;
        float sc = gamma[t] * rsqrtf(var + 1e-5f);
        scs[t] = sc;
        shs[t] = beta[t] - mean * sc;
    }

    const int lane = t & 63;
    const int w = t >> 6;
    const int rrow = lane & 15;
    const int q = lane >> 4;
    const int rowbase = blockIdx.x * 128 + w * 32;
    const int ar0 = rowbase + rrow;
    const int ar1 = rowbase + 16 + rrow;
    const int ar0c = (ar0 < N) ? ar0 : (N - 1);
    const int ar1c = (ar1 < N) ? ar1 : (N - 1);

    f32x4 acc0[4], acc1[4];
#pragma unroll
    for (int cb = 0; cb < 4; cb++) {
        acc0[cb][0] = 0.f; acc0[cb][1] = 0.f; acc0[cb][2] = 0.f; acc0[cb][3] = 0.f;
        acc1[cb][0] = 0.f; acc1[cb][1] = 0.f; acc1[cb][2] = 0.f; acc1[cb][3] = 0.f;
    }
    __syncthreads();

#pragma unroll
    for (int ks = 0; ks < 4; ks++) {
        const int k0 = ks * 32 + q * 8;
        bf16x8 hv0 = *(const bf16x8*)(hb + (size_t)ar0c * 128 + k0);
        bf16x8 hv1 = *(const bf16x8*)(hb + (size_t)ar1c * 128 + k0);
        bf16x8 a0, a1;
#pragma unroll
        for (int i = 0; i < 8; i++) {
            float sc = scs[k0 + i], sh = shs[k0 + i];
            a0[i] = (__bf16)tanhf(fmaf((float)hv0[i], sc, sh));
            a1[i] = (__bf16)tanhf(fmaf((float)hv1[i], sc, sh));
        }
#pragma unroll
        for (int cb = 0; cb < 4; cb++) {
            int byte = (cb * 16 + rrow) * 256 + ks * 64 + q * 16;
            byte ^= ((rrow & 7) << 4);
            bf16x8 b = *(const bf16x8*)(Wl + byte);
            acc0[cb] = __builtin_amdgcn_mfma_f32_16x16x32_bf16(a0, b, acc0[cb], 0, 0, 0);
            acc1[cb] = __builtin_amdgcn_mfma_f32_16x16x32_bf16(a1, b, acc1[cb], 0, 0, 0);
        }
    }

#pragma unroll
    for (int cb = 0; cb < 4; cb++) {
        const int col = cb * 16 + rrow;
        const bool isRel = (col < 32);
        const int cc = isRel ? col : (col - 32);
        const float bc = isRel ? 0.f : b2[cc];
#pragma unroll
        for (int r = 0; r < 4; r++) {
            int rr0 = rowbase + 4 * q + r;
            if (rr0 < N) {
                if (isRel) y2b[(size_t)rr0 * 32 + cc] = (__bf16)acc0[cb][r];
                else       out[(size_t)rr0 * 32 + cc] = acc0[cb][r] + bc;
            }
            int rr1 = rowbase + 16 + 4 * q + r;
            if (rr1 < N) {
                if (isRel) y2b[(size_t)rr1 * 32 + cc] = (__bf16)acc1[cb][r];
                else       out[(size_t)rr1 * 32 + cc] = acc1[cb][r] + bc;
            }
        }
    }
}

// out[row] += sum w*y2_bf[src]; quarter-wave per edge (16 lanes x ushort2
// = full 64B y2 row), 4 edges/wave-iter.
__global__ __launch_bounds__(256) void spmm2_k(
    const __bf16* __restrict__ y2b, const int* __restrict__ cntg,
    const unsigned* __restrict__ bins, const int* __restrict__ ovfcnt,
    const int4* __restrict__ ovf, float* __restrict__ out, int N) {
    const int lane = threadIdx.x & 63;
    const int qs = lane >> 4;       // edge slot 0..3
    const int fp = lane & 15;       // feature pair (2fp, 2fp+1)
    const int row = (blockIdx.x * 256 + threadIdx.x) >> 6;
    if (row >= N) return;
    int cf = cntg[row];
    int cnt = cf > CAP ? CAP : cf;
    unsigned eg = 0u;
    if (lane < cnt) eg = bins[(size_t)row * CAP + lane];
    float ax = 0.f, ay = 0.f;
    for (int j = 0; j < cnt; j += 8) {
        int ss[2]; float ww[2]; unsigned uv[2];
#pragma unroll
        for (int k = 0; k < 2; k++) {
            int idx = j + 4 * k + qs;
            bool ok = idx < cnt;
            unsigned r = (unsigned)__shfl((int)eg, idx);
            ss[k] = ok ? (int)(r >> 16) : 0;
            ww[k] = ok ? __uint_as_float((r & 0xFFFFu) << 16) : 0.f;
        }
#pragma unroll
        for (int k = 0; k < 2; k++)
            uv[k] = *(const unsigned*)((const char*)y2b + (size_t)ss[k] * 64 + fp * 4);
#pragma unroll
        for (int k = 0; k < 2; k++) {
            ax = fmaf(ww[k], __uint_as_float((uv[k] & 0xFFFFu) << 16), ax);
            ay = fmaf(ww[k], __uint_as_float(uv[k] & 0xFFFF0000u), ay);
        }
    }
    if (cf > CAP && qs == 0) {   // rare heavy row; only qs0 (combined below)
        int nv = *ovfcnt; if (nv > OVF_CAP) nv = OVF_CAP;
        for (int i = 0; i < nv; i++) {
            int4 t = ovf[i];
            if (t.y == row) {
                float w = __uint_as_float((unsigned)t.z);
                unsigned u = *(const unsigned*)((const char*)y2b + (size_t)t.x * 64 + fp * 4);
                ax = fmaf(w, __uint_as_float((u & 0xFFFFu) << 16), ax);
                ay = fmaf(w, __uint_as_float(u & 0xFFFF0000u), ay);
            }
        }
    }
    ax += __shfl_xor(ax, 16); ax += __shfl_xor(ax, 32);
    ay += __shfl_xor(ay, 16); ay += __shfl_xor(ay, 32);
    if (qs == 0) {
        float2* p = (float2*)((char*)out + (size_t)row * 128 + fp * 8);
        float2 c = *p;
        c.x += ax; c.y += ay;
        *p = c;
    }
}

extern "C" void kernel_launch(void* const* d_in, const int* in_sizes, int n_in,
                              void* d_out, int out_size, void* d_ws, size_t ws_size,
                              hipStream_t stream) {
    const float* x      = (const float*)d_in[0];
    const float* ea     = (const float*)d_in[1];
    const float* W1rel  = (const float*)d_in[2];
    const float* b1     = (const float*)d_in[3];
    const float* W1root = (const float*)d_in[4];
    const float* gamma  = (const float*)d_in[5];
    const float* beta   = (const float*)d_in[6];
    const float* W2rel  = (const float*)d_in[7];
    const float* b2     = (const float*)d_in[8];
    const float* W2root = (const float*)d_in[9];
    const void*  ei     = d_in[10];

    const int N = in_sizes[0] / 64;   // 50000
    const int E = in_sizes[1];        // 800000
    const int nbg = (N + 127) / 128;  // gemm blocks (128 rows each)

    char* ws = (char*)d_ws;
    size_t off = 0;
    int*      gcnt    = (int*)     (ws + off); off += NB * 4;
    int*      ovfcnt  = (int*)     (ws + off); off += 256;
    float*    bnsum   = (float*)   (ws + off); off += 512;
    float*    bnsq    = (float*)   (ws + off); off += 512;
    int*      cnt     = (int*)     (ws + off); off += ((size_t)N * 4 + 255) & ~255ull;
    __bf16*   xb      = (__bf16*)  (ws + off); off += (size_t)N * 64 * 2;     // 6.4 MB
    __bf16*   aggb    = (__bf16*)  (ws + off); off += (size_t)N * 64 * 2;     // 6.4 MB
    __bf16*   hb      = (__bf16*)  (ws + off); off += (size_t)N * 128 * 2;    // 12.8 MB
    __bf16*   y2b     = (__bf16*)  (ws + off); off += (size_t)N * 32 * 2;     // 3.2 MB
    uint2*    part    = (uint2*)   (ws + off); off += (size_t)NB * CAPB * 8;  // 8.4 MB
    unsigned* bins    = (unsigned*)(ws + off); off += (size_t)N * CAP * 4;    // 6.4 MB
    int4*     ovf     = (int4*)    (ws + off); off += (size_t)OVF_CAP * 16;   // 2 MB
    __bf16*   W1t     = (__bf16*)  (ws + off); off += 128 * 128 * 2;
    __bf16*   W2t     = (__bf16*)  (ws + off); off += 64 * 128 * 2;

    init_k<<<96, 256, 0, stream>>>(W1rel, W1root, W2rel, W2root, W1t, W2t,
                                   gcnt, ovfcnt, bnsum, bnsq);
    const int xcB = (N * 8 + 255) / 256;
    const int partB = (E + CHUNK - 1) / CHUNK;
    partx_k<<<xcB + partB, 256, 0, stream>>>(x, xb, xcB, ea, ei, gcnt, part,
                                             ovfcnt, ovf, E, N);
    binscat_k<<<NB, 256, 0, stream>>>(gcnt, part, bins, cnt, ovfcnt, ovf, N);
    const int rowBlocks = (N * 64 + 255) / 256;
    spmm1_k<<<rowBlocks, 256, 0, stream>>>(xb, cnt, bins, ovfcnt, ovf, aggb, N);
    gemm1_k<<<nbg, 256, 0, stream>>>(aggb, xb, W1t, b1, hb, bnsum, bnsq, N);
    gemm2_k<<<nbg, 256, 0, stream>>>(hb, bnsum, bnsq, gamma, beta, W2t, b2, y2b,
                                     (float*)d_out, N);
    spmm2_k<<<rowBlocks, 256, 0, stream>>>(y2b, cnt, bins, ovfcnt, ovf, (float*)d_out, N);
}

// Round 15
// 107.552 us; speedup vs baseline: 1.1010x; 1.0456x over previous
//
#include <hip/hip_runtime.h>
#include <hip/hip_bf16.h>

// ---------------------------------------------------------------------------
// GCN 2-layer + BN + tanh. All dense streams bf16 (f32 accum).
//   init_k:    W -> bf16 transposed; zero-inits counters. (tiny)
//   partx_k:   [blocks 0..xcB)   x -> bf16 (BW-bound)
//              [blocks xcB..end) partition E edges into NB=256 dst-buckets.
//   binscat_k: per-bucket LDS scatter -> per-dst 4B bins (src:u16|w:bf16)+cnt.
//   spmm1_k:   one wave/row, half-wave per edge: agg_bf = bf16(sum w*x[src]).
//   gemm1_k:   STATS-ONLY: h = [agg|x]@W1t^T + b1 in regs (MFMA, W1 in LDS
//              swizzled, 2 row-tiles/wave); BN partials -> f32 atomics.
//              NO h store (gemm2 recomputes h -- saves the 12.8 MB roundtrip).
//   gemm2_k:   recompute h via MFMA; BN finalize; D-frag -> LDS Ht (aliases
//              W1 buffer, 49.5 KB static total < 64 KB limit) -> A-frag;
//              act=tanh(BN(h)); y2_bf=act@W2rel, out=act@W2root+b2.
//   spmm2_k:   one wave/row, quarter-wave per edge: out += sum w*y2_bf[src].
// MFMA 16x16x32 bf16 lane maps (m89-verified D):
//   A: row=lane&15, k=8*(lane>>4)+i ; B: col=lane&15 (Wt[n][k]) ;
//   D: col=lane&15, row=4*(lane>>4)+reg
// LDS swizzle (256B rows): byte ^= (row&7)<<4
// NOTE: 4B bin records assume N <= 65536 (harness N=50000).
// R10 lesson (rediagnosed): 69.5 KB static LDS > 64 KB limit -> silent launch
// failure. This fusion keeps every kernel <= 50 KB static LDS.
// ---------------------------------------------------------------------------

#define NB 256
#define CAPB 4096
#define LCAP 16
#define CHUNK 2048
#define CAP 32
#define MAXROWS 196
#define OVF_CAP 131072

typedef __bf16 bf16x8 __attribute__((ext_vector_type(8)));
typedef float f32x4 __attribute__((ext_vector_type(4)));

__device__ __forceinline__ void atomAdd(float* p, float v) { unsafeAtomicAdd(p, v); }

__device__ __forceinline__ unsigned packrec(unsigned src, float w) {
    __bf16 bw = (__bf16)w;
    unsigned short us = *(unsigned short*)&bw;
    return (src << 16) | (unsigned)us;
}

// W -> transposed bf16; counters zeroed (block 0). 96 blocks.
__global__ __launch_bounds__(256) void init_k(
    const float* __restrict__ W1rel, const float* __restrict__ W1root,
    const float* __restrict__ W2rel, const float* __restrict__ W2root,
    __bf16* __restrict__ W1t, __bf16* __restrict__ W2t,
    int* __restrict__ gcnt, int* __restrict__ ovfcnt,
    float* __restrict__ bnsum, float* __restrict__ bnsq) {
    if (blockIdx.x == 0) {
        int t = threadIdx.x;
        if (t < NB) gcnt[t] = 0;
        if (t == 0) *ovfcnt = 0;
        if (t < 128) { bnsum[t] = 0.f; bnsq[t] = 0.f; }
    }
    int idx = blockIdx.x * 256 + threadIdx.x;
    if (idx < 128 * 128) {
        int n = idx >> 7, k = idx & 127;
        float v = (k < 64) ? W1rel[k * 128 + n] : W1root[(k - 64) * 128 + n];
        W1t[n * 128 + k] = (__bf16)v;
    } else if (idx < 128 * 128 + 64 * 128) {
        int j = idx - 128 * 128;
        int n = j >> 7, k = j & 127;
        float v = (n < 32) ? W2rel[k * 32 + n] : W2root[k * 32 + (n - 32)];
        W2t[n * 128 + k] = (__bf16)v;
    }
}

// Fused: x->bf16 conversion blocks + edge-partition blocks (independent work).
// Record: u32 ((dstloc<<24)|src), u32 w_bits(f32). (src<2^24, dstloc<196)
__global__ __launch_bounds__(256) void partx_k(
    const float* __restrict__ x, __bf16* __restrict__ xb, int xcB,
    const float* __restrict__ ea, const void* __restrict__ ei,
    int* __restrict__ gcnt, uint2* __restrict__ part,
    int* __restrict__ ovfcnt, int4* __restrict__ ovf, int E, int N) {
    __shared__ int s_flag;
    __shared__ int hist[NB];
    __shared__ int gb[NB];
    __shared__ uint2 stage[NB * LCAP];   // 32 KB

    if ((int)blockIdx.x < xcB) {
        int j = blockIdx.x * 256 + threadIdx.x;
        if (j < N * 8) {
            const float4* xs = (const float4*)(x + (size_t)j * 8);
            float4 a = xs[0], b = xs[1];
            bf16x8 v;
            v[0] = (__bf16)a.x; v[1] = (__bf16)a.y; v[2] = (__bf16)a.z; v[3] = (__bf16)a.w;
            v[4] = (__bf16)b.x; v[5] = (__bf16)b.y; v[6] = (__bf16)b.z; v[7] = (__bf16)b.w;
            *(bf16x8*)(xb + (size_t)j * 8) = v;
        }
        return;
    }
    const int pb = blockIdx.x - xcB;

    if (threadIdx.x < 64) {
        const long long* p = (const long long*)ei;
        long long v = p[threadIdx.x & 15];
        int ok = (v >= 0 && v < (long long)N);
        unsigned long long m = __ballot(ok);
        if (threadIdx.x == 0) s_flag = (~m == 0ull) ? 1 : 0;
    }
    for (int i = threadIdx.x; i < NB; i += 256) hist[i] = 0;
    __syncthreads();
    const bool is64 = (s_flag != 0);

    const int base = pb * CHUNK + threadIdx.x * 8;
    int n = E - base; n = n < 0 ? 0 : (n > 8 ? 8 : n);

    int srcs[8], dsts[8]; float wv[8];
    if (n > 0) {
        if (is64) {
            const long long* p = (const long long*)ei;
            if (n == 8 && ((E & 1) == 0)) {
#pragma unroll
                for (int k = 0; k < 4; k++) {
                    int4 a = *(const int4*)(p + base + 2 * k);
                    srcs[2 * k] = a.x; srcs[2 * k + 1] = a.z;
                }
#pragma unroll
                for (int k = 0; k < 4; k++) {
                    int4 b = *(const int4*)(p + E + base + 2 * k);
                    dsts[2 * k] = b.x; dsts[2 * k + 1] = b.z;
                }
            } else {
                for (int k = 0; k < n; k++) { srcs[k] = (int)p[base + k]; dsts[k] = (int)p[E + base + k]; }
            }
        } else {
            const int* p = (const int*)ei;
            if (n == 8 && ((E & 3) == 0)) {
                int4 a0 = *(const int4*)(p + base);
                int4 a1 = *(const int4*)(p + base + 4);
                srcs[0] = a0.x; srcs[1] = a0.y; srcs[2] = a0.z; srcs[3] = a0.w;
                srcs[4] = a1.x; srcs[5] = a1.y; srcs[6] = a1.z; srcs[7] = a1.w;
                int4 b0 = *(const int4*)(p + E + base);
                int4 b1 = *(const int4*)(p + E + base + 4);
                dsts[0] = b0.x; dsts[1] = b0.y; dsts[2] = b0.z; dsts[3] = b0.w;
                dsts[4] = b1.x; dsts[5] = b1.y; dsts[6] = b1.z; dsts[7] = b1.w;
            } else {
                for (int k = 0; k < n; k++) { srcs[k] = p[base + k]; dsts[k] = p[E + base + k]; }
            }
        }
        if (n == 8) {
            float4 w0 = *(const float4*)(ea + base);
            float4 w1 = *(const float4*)(ea + base + 4);
            wv[0] = w0.x; wv[1] = w0.y; wv[2] = w0.z; wv[3] = w0.w;
            wv[4] = w1.x; wv[5] = w1.y; wv[6] = w1.z; wv[7] = w1.w;
        } else {
            for (int k = 0; k < n; k++) wv[k] = ea[base + k];
        }

        int bk[8], pos[8], loc[8];
#pragma unroll
        for (int k = 0; k < 8; k++) {
            if (k < n) {
                unsigned b = ((unsigned)dsts[k] << 8) / (unsigned)N;
                int r0 = (int)((b * (unsigned)N + 255u) >> 8);
                bk[k] = (int)b;
                loc[k] = dsts[k] - r0;
                pos[k] = atomicAdd(&hist[b], 1);
            }
        }
#pragma unroll
        for (int k = 0; k < 8; k++) {
            if (k < n) {
                unsigned packed = ((unsigned)loc[k] << 24) | (unsigned)srcs[k];
                if (pos[k] < LCAP) {
                    stage[bk[k] * LCAP + pos[k]] = make_uint2(packed, __float_as_uint(wv[k]));
                } else {
                    int g = atomicAdd(&gcnt[bk[k]], 1);
                    if (g < CAPB) {
                        part[(size_t)bk[k] * CAPB + g] = make_uint2(packed, __float_as_uint(wv[k]));
                    } else {
                        int o = atomicAdd(ovfcnt, 1);
                        if (o < OVF_CAP) ovf[o] = make_int4(srcs[k], dsts[k], (int)__float_as_uint(wv[k]), 0);
                    }
                }
            }
        }
    }
    __syncthreads();
    if (threadIdx.x < NB) {
        int h = hist[threadIdx.x]; if (h > LCAP) h = LCAP;
        hist[threadIdx.x] = h;
        gb[threadIdx.x] = h ? atomicAdd(&gcnt[threadIdx.x], h) : 0;
    }
    __syncthreads();
    const int wvi = threadIdx.x >> 6;
    const int sub = (threadIdx.x >> 4) & 3;
    const int f = threadIdx.x & 15;
    for (int round = 0; round < 16; ++round) {
        int b = wvi * 64 + round * 4 + sub;
        int h = hist[b];
        if (f < h) {
            int g = gb[b] + f;
            uint2 r = stage[b * LCAP + f];
            if (g < CAPB) {
                part[(size_t)b * CAPB + g] = r;
            } else {
                int r0 = (b * N + 255) >> 8;
                int dst = r0 + (int)(r.x >> 24);
                int o = atomicAdd(ovfcnt, 1);
                if (o < OVF_CAP) ovf[o] = make_int4((int)(r.x & 0xFFFFFFu), dst, (int)r.y, 0);
            }
        }
    }
}

// Per-bucket: scatter records into per-dst 4B bins in LDS, write out dense.
__global__ __launch_bounds__(256) void binscat_k(
    const int* __restrict__ gcnt, const uint2* __restrict__ part,
    unsigned* __restrict__ bins, int* __restrict__ cnt,
    int* __restrict__ ovfcnt, int4* __restrict__ ovf, int N) {
    __shared__ unsigned stage[MAXROWS * CAP];   // 25 KB
    __shared__ int lcnt[MAXROWS];
    const int b = blockIdx.x;
    const int r0 = (b * N + 255) >> 8;
    int r1 = ((b + 1) * N + 255) >> 8; if (r1 > N) r1 = N;
    const int rows = r1 - r0;
    for (int i = threadIdx.x; i < rows; i += 256) lcnt[i] = 0;
    __syncthreads();

    int m = gcnt[b]; if (m > CAPB) m = CAPB;
    const uint2* pb = part + (size_t)b * CAPB;
    for (int i = threadIdx.x; i < m; i += 256) {
        uint2 r = pb[i];
        int d = r.x >> 24;
        unsigned src = r.x & 0xFFFFFFu;
        float w = __uint_as_float(r.y);
        int pos = atomicAdd(&lcnt[d], 1);
        if (pos < CAP) {
            stage[d * CAP + pos] = packrec(src, w);
        } else {
            int o = atomicAdd(ovfcnt, 1);
            if (o < OVF_CAP) ovf[o] = make_int4((int)src, r0 + d, (int)r.y, 0);
        }
    }
    __syncthreads();
    uint4* dst = (uint4*)(bins + (size_t)r0 * CAP);
    const uint4* srcp = (const uint4*)stage;
    for (int i = threadIdx.x; i < rows * (CAP / 4); i += 256) dst[i] = srcp[i];
    for (int i = threadIdx.x; i < rows; i += 256) cnt[r0 + i] = lcnt[i];
}

// agg_bf[row] = bf16(sum w*x_bf[src]); half-wave per edge, ushort2 gathers.
__global__ __launch_bounds__(256) void spmm1_k(
    const __bf16* __restrict__ xb, const int* __restrict__ cntg,
    const unsigned* __restrict__ bins, const int* __restrict__ ovfcnt,
    const int4* __restrict__ ovf, __bf16* __restrict__ aggb, int N) {
    const int lane = threadIdx.x & 63;
    const int sub = lane >> 5;
    const int fp = lane & 31;
    const int row = (blockIdx.x * 256 + threadIdx.x) >> 6;
    if (row >= N) return;
    int cf = cntg[row];
    int cnt = cf > CAP ? CAP : cf;
    unsigned eg = 0u;
    if (lane < cnt) eg = bins[(size_t)row * CAP + lane];
    float ax = 0.f, ay = 0.f;
    for (int j = 0; j < cnt; j += 8) {
        int ss[4]; float ww[4]; unsigned uv[4];
#pragma unroll
        for (int k = 0; k < 4; k++) {
            int idx = j + 2 * k + sub;
            bool ok = idx < cnt;
            unsigned r = (unsigned)__shfl((int)eg, idx);
            ss[k] = ok ? (int)(r >> 16) : 0;
            ww[k] = ok ? __uint_as_float((r & 0xFFFFu) << 16) : 0.f;
        }
#pragma unroll
        for (int k = 0; k < 4; k++)
            uv[k] = *(const unsigned*)((const char*)xb + (size_t)ss[k] * 128 + fp * 4);
#pragma unroll
        for (int k = 0; k < 4; k++) {
            ax = fmaf(ww[k], __uint_as_float((uv[k] & 0xFFFFu) << 16), ax);
            ay = fmaf(ww[k], __uint_as_float(uv[k] & 0xFFFF0000u), ay);
        }
    }
    if (cf > CAP && sub == 0) {
        int nv = *ovfcnt; if (nv > OVF_CAP) nv = OVF_CAP;
        for (int i = 0; i < nv; i++) {
            int4 t = ovf[i];
            if (t.y == row) {
                float w = __uint_as_float((unsigned)t.z);
                unsigned u = *(const unsigned*)((const char*)xb + (size_t)t.x * 128 + fp * 4);
                ax = fmaf(w, __uint_as_float((u & 0xFFFFu) << 16), ax);
                ay = fmaf(w, __uint_as_float(u & 0xFFFF0000u), ay);
            }
        }
    }
    ax += __shfl_xor(ax, 32);
    ay += __shfl_xor(ay, 32);
    if (sub == 0) {
        __bf16 b0 = (__bf16)ax, b1 = (__bf16)ay;
        unsigned pack = (unsigned)*(unsigned short*)&b0 |
                        ((unsigned)*(unsigned short*)&b1 << 16);
        *(unsigned*)((char*)aggb + (size_t)row * 128 + fp * 4) = pack;
    }
}

// MFMA gemm1 (STATS ONLY): h = [agg|x] @ W1t^T + b1 in regs; BN partials ->
// 256 f32 atomics. No h store.
__global__ __launch_bounds__(256) void gemm1_k(
    const __bf16* __restrict__ aggb, const __bf16* __restrict__ xb,
    const __bf16* __restrict__ W1t, const float* __restrict__ b1,
    float* __restrict__ bnsum, float* __restrict__ bnsq, int N) {
    __shared__ char Wl[128 * 256];        // 32 KB, swizzled
    __shared__ float redS[4][128];
    __shared__ float redQ[4][128];
    const int t = threadIdx.x;
    for (int i = t; i < 2048; i += 256) {
        int byte = i * 16;
        int row = byte >> 8;
        int sw = byte ^ ((row & 7) << 4);
        *(uint4*)(Wl + sw) = *(const uint4*)((const char*)W1t + byte);
    }

    const int lane = t & 63;
    const int w = t >> 6;
    const int rrow = lane & 15;
    const int q = lane >> 4;
    const int rowbase = blockIdx.x * 128 + w * 32;
    const int ar0 = rowbase + rrow;
    const int ar1 = rowbase + 16 + rrow;
    const int ar0c = (ar0 < N) ? ar0 : (N - 1);
    const int ar1c = (ar1 < N) ? ar1 : (N - 1);

    f32x4 acc0[8], acc1[8];
#pragma unroll
    for (int cb = 0; cb < 8; cb++) {
        acc0[cb][0] = 0.f; acc0[cb][1] = 0.f; acc0[cb][2] = 0.f; acc0[cb][3] = 0.f;
        acc1[cb][0] = 0.f; acc1[cb][1] = 0.f; acc1[cb][2] = 0.f; acc1[cb][3] = 0.f;
    }
    __syncthreads();

#pragma unroll
    for (int ks = 0; ks < 4; ks++) {
        const int koff = (ks & 1) * 32 + q * 8;
        const __bf16* base = (ks < 2) ? aggb : xb;
        bf16x8 a0 = *(const bf16x8*)(base + (size_t)ar0c * 64 + koff);
        bf16x8 a1 = *(const bf16x8*)(base + (size_t)ar1c * 64 + koff);
#pragma unroll
        for (int cb = 0; cb < 8; cb++) {
            int byte = (cb * 16 + rrow) * 256 + ks * 64 + q * 16;
            byte ^= ((rrow & 7) << 4);
            bf16x8 b = *(const bf16x8*)(Wl + byte);
            acc0[cb] = __builtin_amdgcn_mfma_f32_16x16x32_bf16(a0, b, acc0[cb], 0, 0, 0);
            acc1[cb] = __builtin_amdgcn_mfma_f32_16x16x32_bf16(a1, b, acc1[cb], 0, 0, 0);
        }
    }

    float s[8], qs[8];
#pragma unroll
    for (int cb = 0; cb < 8; cb++) {
        const int col = cb * 16 + rrow;
        const float bc = b1[col];
        float ls = 0.f, lq = 0.f;
#pragma unroll
        for (int r = 0; r < 4; r++) {
            int rr0 = rowbase + 4 * q + r;
            if (rr0 < N) {
                float v = acc0[cb][r] + bc;
                ls += v; lq += v * v;
            }
            int rr1 = rowbase + 16 + 4 * q + r;
            if (rr1 < N) {
                float v = acc1[cb][r] + bc;
                ls += v; lq += v * v;
            }
        }
        s[cb] = ls; qs[cb] = lq;
    }
#pragma unroll
    for (int cb = 0; cb < 8; cb++) {
        s[cb] += __shfl_xor(s[cb], 16);  s[cb] += __shfl_xor(s[cb], 32);
        qs[cb] += __shfl_xor(qs[cb], 16); qs[cb] += __shfl_xor(qs[cb], 32);
    }
    if (q == 0) {
#pragma unroll
        for (int cb = 0; cb < 8; cb++) {
            redS[w][cb * 16 + rrow] = s[cb];
            redQ[w][cb * 16 + rrow] = qs[cb];
        }
    }
    __syncthreads();
    if (t < 128) {
        atomAdd(&bnsum[t], redS[0][t] + redS[1][t] + redS[2][t] + redS[3][t]);
    } else {
        int c = t - 128;
        atomAdd(&bnsq[c], redQ[0][c] + redQ[1][c] + redQ[2][c] + redQ[3][c]);
    }
}

// MFMA gemm2 FUSED: recompute h from aggb/xb (phase 1, W1 in LDS), write
// bf16 h to LDS Ht (ALIASES W1 buffer after barrier), BN finalize, then
// act=tanh(BN(h)) -> A-frags from Ht -> layer-2 MFMA (W2 in LDS).
// Static LDS: 32 (Wl alias Ht) + 16 (W2l) + 1.5 KB = 49.5 KB < 64 KB.
__global__ __launch_bounds__(256) void gemm2_k(
    const __bf16* __restrict__ aggb, const __bf16* __restrict__ xb,
    const __bf16* __restrict__ W1t, const float* __restrict__ b1,
    const float* __restrict__ bnsum, const float* __restrict__ bnsq,
    const float* __restrict__ gamma, const float* __restrict__ beta,
    const __bf16* __restrict__ W2t, const float* __restrict__ b2,
    __bf16* __restrict__ y2b, float* __restrict__ out, int N) {
    __shared__ char Wl[128 * 256];        // 32 KB: W1 (phase 1) then Ht (phase 2)
    __shared__ char W2l[64 * 256];        // 16 KB: W2, swizzled
    __shared__ float scs[128], shs[128], b1s[128];
    const int t = threadIdx.x;
    for (int i = t; i < 2048; i += 256) {
        int byte = i * 16;
        int row = byte >> 8;
        int sw = byte ^ ((row & 7) << 4);
        *(uint4*)(Wl + sw) = *(const uint4*)((const char*)W1t + byte);
    }
    for (int i = t; i < 1024; i += 256) {
        int byte = i * 16;
        int row = byte >> 8;
        int sw = byte ^ ((row & 7) << 4);
        *(uint4*)(W2l + sw) = *(const uint4*)((const char*)W2t + byte);
    }
    if (t < 128) {
        float inv = 1.0f / (float)N;
        float mean = bnsum[t] * inv;
        float var = bnsq[t] * inv - mean * mean;
        if (var < 0.f) var = 0.f;
        float sc = gamma[t] * rsqrtf(var + 1e-5f);
        scs[t] = sc;
        shs[t] = beta[t] - mean * sc;
        b1s[t] = b1[t];
    }

    const int lane = t & 63;
    const int w = t >> 6;
    const int rrow = lane & 15;
    const int q = lane >> 4;
    const int rowbase = blockIdx.x * 128 + w * 32;
    const int ar0 = rowbase + rrow;
    const int ar1 = rowbase + 16 + rrow;
    const int ar0c = (ar0 < N) ? ar0 : (N - 1);
    const int ar1c = (ar1 < N) ? ar1 : (N - 1);

    // ---- phase 1: recompute h ----
    f32x4 acc0[8], acc1[8];
#pragma unroll
    for (int cb = 0; cb < 8; cb++) {
        acc0[cb][0] = 0.f; acc0[cb][1] = 0.f; acc0[cb][2] = 0.f; acc0[cb][3] = 0.f;
        acc1[cb][0] = 0.f; acc1[cb][1] = 0.f; acc1[cb][2] = 0.f; acc1[cb][3] = 0.f;
    }
    __syncthreads();

#pragma unroll
    for (int ks = 0; ks < 4; ks++) {
        const int koff = (ks & 1) * 32 + q * 8;
        const __bf16* base = (ks < 2) ? aggb : xb;
        bf16x8 a0 = *(const bf16x8*)(base + (size_t)ar0c * 64 + koff);
        bf16x8 a1 = *(const bf16x8*)(base + (size_t)ar1c * 64 + koff);
#pragma unroll
        for (int cb = 0; cb < 8; cb++) {
            int byte = (cb * 16 + rrow) * 256 + ks * 64 + q * 16;
            byte ^= ((rrow & 7) << 4);
            bf16x8 b = *(const bf16x8*)(Wl + byte);
            acc0[cb] = __builtin_amdgcn_mfma_f32_16x16x32_bf16(a0, b, acc0[cb], 0, 0, 0);
            acc1[cb] = __builtin_amdgcn_mfma_f32_16x16x32_bf16(a1, b, acc1[cb], 0, 0, 0);
        }
    }
    __syncthreads();   // all W1 reads done; Wl reusable as Ht

    // D-frag -> Ht (bf16, swizzled rows of 256B): col=cb*16+rrow, lrow=w*32+4q+r(+16)
#pragma unroll
    for (int cb = 0; cb < 8; cb++) {
        const int col = cb * 16 + rrow;
        const float bc = b1s[col];
#pragma unroll
        for (int r = 0; r < 4; r++) {
            int lrow0 = w * 32 + 4 * q + r;
            int byte0 = (lrow0 * 256 + col * 2) ^ ((lrow0 & 7) << 4);
            *(__bf16*)(Wl + byte0) = (__bf16)(acc0[cb][r] + bc);
            int lrow1 = lrow0 + 16;
            int byte1 = (lrow1 * 256 + col * 2) ^ ((lrow1 & 7) << 4);
            *(__bf16*)(Wl + byte1) = (__bf16)(acc1[cb][r] + bc);
        }
    }
    __syncthreads();

    // ---- phase 2: act = tanh(h*sc+sh) from Ht; layer-2 MFMA ----
    f32x4 bcc0[4], bcc1[4];
#pragma unroll
    for (int cb = 0; cb < 4; cb++) {
        bcc0[cb][0] = 0.f; bcc0[cb][1] = 0.f; bcc0[cb][2] = 0.f; bcc0[cb][3] = 0.f;
        bcc1[cb][0] = 0.f; bcc1[cb][1] = 0.f; bcc1[cb][2] = 0.f; bcc1[cb][3] = 0.f;
    }
    const int lrowA0 = w * 32 + rrow;
    const int lrowA1 = lrowA0 + 16;

#pragma unroll
    for (int ks = 0; ks < 4; ks++) {
        const int k0 = ks * 32 + q * 8;
        int byteA0 = (lrowA0 * 256 + k0 * 2) ^ ((lrowA0 & 7) << 4);
        int byteA1 = (lrowA1 * 256 + k0 * 2) ^ ((lrowA1 & 7) << 4);
        bf16x8 hv0 = *(const bf16x8*)(Wl + byteA0);
        bf16x8 hv1 = *(const bf16x8*)(Wl + byteA1);
        bf16x8 a0, a1;
#pragma unroll
        for (int i = 0; i < 8; i++) {
            float sc = scs[k0 + i], sh = shs[k0 + i];
            a0[i] = (__bf16)tanhf(fmaf((float)hv0[i], sc, sh));
            a1[i] = (__bf16)tanhf(fmaf((float)hv1[i], sc, sh));
        }
#pragma unroll
        for (int cb = 0; cb < 4; cb++) {
            int byte = (cb * 16 + rrow) * 256 + ks * 64 + q * 16;
            byte ^= ((rrow & 7) << 4);
            bf16x8 b = *(const bf16x8*)(W2l + byte);
            bcc0[cb] = __builtin_amdgcn_mfma_f32_16x16x32_bf16(a0, b, bcc0[cb], 0, 0, 0);
            bcc1[cb] = __builtin_amdgcn_mfma_f32_16x16x32_bf16(a1, b, bcc1[cb], 0, 0, 0);
        }
    }

#pragma unroll
    for (int cb = 0; cb < 4; cb++) {
        const int col = cb * 16 + rrow;
        const bool isRel = (col < 32);
        const int cc = isRel ? col : (col - 32);
        const float bc = isRel ? 0.f : b2[cc];
#pragma unroll
        for (int r = 0; r < 4; r++) {
            int rr0 = rowbase + 4 * q + r;
            if (rr0 < N) {
                if (isRel) y2b[(size_t)rr0 * 32 + cc] = (__bf16)bcc0[cb][r];
                else       out[(size_t)rr0 * 32 + cc] = bcc0[cb][r] + bc;
            }
            int rr1 = rowbase + 16 + 4 * q + r;
            if (rr1 < N) {
                if (isRel) y2b[(size_t)rr1 * 32 + cc] = (__bf16)bcc1[cb][r];
                else       out[(size_t)rr1 * 32 + cc] = bcc1[cb][r] + bc;
            }
        }
    }
}

// out[row] += sum w*y2_bf[src]; quarter-wave per edge (16 lanes x ushort2
// = full 64B y2 row), 4 edges/wave-iter.
__global__ __launch_bounds__(256) void spmm2_k(
    const __bf16* __restrict__ y2b, const int* __restrict__ cntg,
    const unsigned* __restrict__ bins, const int* __restrict__ ovfcnt,
    const int4* __restrict__ ovf, float* __restrict__ out, int N) {
    const int lane = threadIdx.x & 63;
    const int qs = lane >> 4;       // edge slot 0..3
    const int fp = lane & 15;       // feature pair (2fp, 2fp+1)
    const int row = (blockIdx.x * 256 + threadIdx.x) >> 6;
    if (row >= N) return;
    int cf = cntg[row];
    int cnt = cf > CAP ? CAP : cf;
    unsigned eg = 0u;
    if (lane < cnt) eg = bins[(size_t)row * CAP + lane];
    float ax = 0.f, ay = 0.f;
    for (int j = 0; j < cnt; j += 8) {
        int ss[2]; float ww[2]; unsigned uv[2];
#pragma unroll
        for (int k = 0; k < 2; k++) {
            int idx = j + 4 * k + qs;
            bool ok = idx < cnt;
            unsigned r = (unsigned)__shfl((int)eg, idx);
            ss[k] = ok ? (int)(r >> 16) : 0;
            ww[k] = ok ? __uint_as_float((r & 0xFFFFu) << 16) : 0.f;
        }
#pragma unroll
        for (int k = 0; k < 2; k++)
            uv[k] = *(const unsigned*)((const char*)y2b + (size_t)ss[k] * 64 + fp * 4);
#pragma unroll
        for (int k = 0; k < 2; k++) {
            ax = fmaf(ww[k], __uint_as_float((uv[k] & 0xFFFFu) << 16), ax);
            ay = fmaf(ww[k], __uint_as_float(uv[k] & 0xFFFF0000u), ay);
        }
    }
    if (cf > CAP && qs == 0) {
        int nv = *ovfcnt; if (nv > OVF_CAP) nv = OVF_CAP;
        for (int i = 0; i < nv; i++) {
            int4 t = ovf[i];
            if (t.y == row) {
                float w = __uint_as_float((unsigned)t.z);
                unsigned u = *(const unsigned*)((const char*)y2b + (size_t)t.x * 64 + fp * 4);
                ax = fmaf(w, __uint_as_float((u & 0xFFFFu) << 16), ax);
                ay = fmaf(w, __uint_as_float(u & 0xFFFF0000u), ay);
            }
        }
    }
    ax += __shfl_xor(ax, 16); ax += __shfl_xor(ax, 32);
    ay += __shfl_xor(ay, 16); ay += __shfl_xor(ay, 32);
    if (qs == 0) {
        float2* p = (float2*)((char*)out + (size_t)row * 128 + fp * 8);
        float2 c = *p;
        c.x += ax; c.y += ay;
        *p = c;
    }
}

extern "C" void kernel_launch(void* const* d_in, const int* in_sizes, int n_in,
                              void* d_out, int out_size, void* d_ws, size_t ws_size,
                              hipStream_t stream) {
    const float* x      = (const float*)d_in[0];
    const float* ea     = (const float*)d_in[1];
    const float* W1rel  = (const float*)d_in[2];
    const float* b1     = (const float*)d_in[3];
    const float* W1root = (const float*)d_in[4];
    const float* gamma  = (const float*)d_in[5];
    const float* beta   = (const float*)d_in[6];
    const float* W2rel  = (const float*)d_in[7];
    const float* b2     = (const float*)d_in[8];
    const float* W2root = (const float*)d_in[9];
    const void*  ei     = d_in[10];

    const int N = in_sizes[0] / 64;   // 50000
    const int E = in_sizes[1];        // 800000
    const int nbg = (N + 127) / 128;  // gemm blocks (128 rows each)

    char* ws = (char*)d_ws;
    size_t off = 0;
    int*      gcnt    = (int*)     (ws + off); off += NB * 4;
    int*      ovfcnt  = (int*)     (ws + off); off += 256;
    float*    bnsum   = (float*)   (ws + off); off += 512;
    float*    bnsq    = (float*)   (ws + off); off += 512;
    int*      cnt     = (int*)     (ws + off); off += ((size_t)N * 4 + 255) & ~255ull;
    __bf16*   xb      = (__bf16*)  (ws + off); off += (size_t)N * 64 * 2;     // 6.4 MB
    __bf16*   aggb    = (__bf16*)  (ws + off); off += (size_t)N * 64 * 2;     // 6.4 MB
    __bf16*   y2b     = (__bf16*)  (ws + off); off += (size_t)N * 32 * 2;     // 3.2 MB
    uint2*    part    = (uint2*)   (ws + off); off += (size_t)NB * CAPB * 8;  // 8.4 MB
    unsigned* bins    = (unsigned*)(ws + off); off += (size_t)N * CAP * 4;    // 6.4 MB
    int4*     ovf     = (int4*)    (ws + off); off += (size_t)OVF_CAP * 16;   // 2 MB
    __bf16*   W1t     = (__bf16*)  (ws + off); off += 128 * 128 * 2;
    __bf16*   W2t     = (__bf16*)  (ws + off); off += 64 * 128 * 2;

    init_k<<<96, 256, 0, stream>>>(W1rel, W1root, W2rel, W2root, W1t, W2t,
                                   gcnt, ovfcnt, bnsum, bnsq);
    const int xcB = (N * 8 + 255) / 256;
    const int partB = (E + CHUNK - 1) / CHUNK;
    partx_k<<<xcB + partB, 256, 0, stream>>>(x, xb, xcB, ea, ei, gcnt, part,
                                             ovfcnt, ovf, E, N);
    binscat_k<<<NB, 256, 0, stream>>>(gcnt, part, bins, cnt, ovfcnt, ovf, N);
    const int rowBlocks = (N * 64 + 255) / 256;
    spmm1_k<<<rowBlocks, 256, 0, stream>>>(xb, cnt, bins, ovfcnt, ovf, aggb, N);
    gemm1_k<<<nbg, 256, 0, stream>>>(aggb, xb, W1t, b1, bnsum, bnsq, N);
    gemm2_k<<<nbg, 256, 0, stream>>>(aggb, xb, W1t, b1, bnsum, bnsq, gamma, beta,
                                     W2t, b2, y2b, (float*)d_out, N);
    spmm2_k<<<rowBlocks, 256, 0, stream>>>(y2b, cnt, bins, ovfcnt, ovf, (float*)d_out, N);
}